// Round 6
// baseline (781.777 us; speedup 1.0000x reference)
//
#include <hip/hip_runtime.h>
#include <math.h>

#define BATCH 1024
#define C0 512
#define HW0 196   // 14*14
#define C1 1024
#define HW1 49    // 7*7
#define K0 100
#define K1 50

// Grid split for the fused pooling kernel
#define G0_BLOCKS ((BATCH * C0) / 4)    // 131072 blocks: feat0, 1 channel per wave, 4 waves/block
#define G1_BLOCKS ((BATCH * C1) / 16)   // 65536 blocks: feat1, 4 channels per wave, 4 waves/block

__device__ __forceinline__ float waveReduceSum(float v) {
#pragma unroll
    for (int off = 32; off > 0; off >>= 1) v += __shfl_xor(v, off, 64);
    return v;
}
__device__ __forceinline__ float waveReduceMax(float v) {
#pragma unroll
    for (int off = 32; off > 0; off >>= 1) v = fmaxf(v, __shfl_xor(v, off, 64));
    return v;
}

// Fused global-average-pool over feat0 and feat1.
// feat0 path: one wave per (b,c) channel: 196 floats = 49 float4 (16B-aligned:
//   196*4B = 784B = 49*16B). Lane l<49 loads float4 #l, wave-reduce, lane0 writes mean.
// feat1 path: channels are 49 floats (196B, not 16B-aligned), so one wave handles 4
//   consecutive channels (196 floats = 49 aligned float4); per-lane segmented add into
//   4 registers (compile-time unrolled -> stays in VGPRs), 4 wave reductions, float4 store.
__global__ __launch_bounds__(256) void pool_fused_kernel(const float* __restrict__ feat0,
                                                         const float* __restrict__ feat1,
                                                         float* __restrict__ pooled0,
                                                         float* __restrict__ pooled1,
                                                         float* __restrict__ accum) {
    if (blockIdx.x == 0 && threadIdx.x < 4) accum[threadIdx.x] = 0.f;  // zero loss accumulators
    const int lane = threadIdx.x & 63;
    const int wv   = threadIdx.x >> 6;

    if (blockIdx.x < G0_BLOCKS) {
        const int ch = (blockIdx.x << 2) + wv;  // (b*C0 + c)
        const float4* p = reinterpret_cast<const float4*>(feat0) + (size_t)ch * 49;
        float s = 0.f;
        if (lane < 49) {
            float4 v = p[lane];
            s = (v.x + v.y) + (v.z + v.w);
        }
        s = waveReduceSum(s);
        if (lane == 0) pooled0[ch] = s * (1.f / 196.f);
    } else {
        const int g = ((blockIdx.x - G0_BLOCKS) << 2) + wv;  // group of 4 channels
        float a0 = 0.f, a1 = 0.f, a2 = 0.f, a3 = 0.f;
        if (lane < 49) {
            float4 v = reinterpret_cast<const float4*>(feat1)[(size_t)g * 49 + lane];
            const int e = lane * 4;
            float vv[4] = {v.x, v.y, v.z, v.w};
#pragma unroll
            for (int j = 0; j < 4; ++j) {
                int ej = e + j;
                int c = (ej >= 147) ? 3 : (ej >= 98) ? 2 : (ej >= 49) ? 1 : 0;
                float x = vv[j];
                a0 += (c == 0) ? x : 0.f;
                a1 += (c == 1) ? x : 0.f;
                a2 += (c == 2) ? x : 0.f;
                a3 += (c == 3) ? x : 0.f;
            }
        }
        a0 = waveReduceSum(a0);
        a1 = waveReduceSum(a1);
        a2 = waveReduceSum(a2);
        a3 = waveReduceSum(a3);
        if (lane == 0) {
            const float inv = 1.f / 49.f;
            float4 o;
            o.x = a0 * inv; o.y = a1 * inv; o.z = a2 * inv; o.w = a3 * inv;
            reinterpret_cast<float4*>(pooled1)[g] = o;
        }
    }
}

// One block per batch row. Stage pooled rows in LDS; thread k computes logit k
// (W0/W1 total 400KB -> L2-resident, reused by all 1024 blocks). Wave 0 / wave 1
// do the two log-sum-exp + weighted NLL reductions and atomicAdd 4 scalars.
__global__ __launch_bounds__(256) void head_ce_kernel(
    const float* __restrict__ pooled0, const float* __restrict__ pooled1,
    const float* __restrict__ W0, const float* __restrict__ b0,
    const float* __restrict__ W1, const float* __restrict__ b1,
    const int* __restrict__ lut0, const int* __restrict__ lut1,
    const float* __restrict__ cw0, const float* __restrict__ cw1,
    const int* __restrict__ target, float* __restrict__ accum) {
    __shared__ float sp0[C0];
    __shared__ float sp1[C1];
    __shared__ float lg0[K0];
    __shared__ float lg1[K1];
    const int b = blockIdx.x;
    const int tid = threadIdx.x;

    for (int i = tid; i < C0; i += 256) sp0[i] = pooled0[(size_t)b * C0 + i];
    for (int i = tid; i < C1; i += 256) sp1[i] = pooled1[(size_t)b * C1 + i];
    __syncthreads();

    if (tid < K0) {
        const float* w = W0 + (size_t)tid * C0;
        float acc0 = 0.f, acc1 = 0.f, acc2 = 0.f, acc3 = 0.f;
        for (int c = 0; c < C0; c += 4) {
            acc0 += sp0[c + 0] * w[c + 0];
            acc1 += sp0[c + 1] * w[c + 1];
            acc2 += sp0[c + 2] * w[c + 2];
            acc3 += sp0[c + 3] * w[c + 3];
        }
        lg0[tid] = b0[tid] + ((acc0 + acc1) + (acc2 + acc3));
    } else if (tid >= 128 && tid < 128 + K1) {
        const int k = tid - 128;
        const float* w = W1 + (size_t)k * C1;
        float acc0 = 0.f, acc1 = 0.f, acc2 = 0.f, acc3 = 0.f;
        for (int c = 0; c < C1; c += 4) {
            acc0 += sp1[c + 0] * w[c + 0];
            acc1 += sp1[c + 1] * w[c + 1];
            acc2 += sp1[c + 2] * w[c + 2];
            acc3 += sp1[c + 3] * w[c + 3];
        }
        lg1[k] = b1[k] + ((acc0 + acc1) + (acc2 + acc3));
    }
    __syncthreads();

    const int wv = tid >> 6;
    const int lane = tid & 63;
    if (wv == 0) {
        // head0: 100 logits, lanes cover [l, l+64]
        float x1 = lg0[lane];  // lane < 64 < K0
        bool has2 = (lane + 64) < K0;
        float x2 = has2 ? lg0[lane + 64] : -3.0e38f;
        float m = waveReduceMax(fmaxf(x1, x2));
        float s = expf(x1 - m) + (has2 ? expf(x2 - m) : 0.f);
        s = waveReduceSum(s);
        if (lane == 0) {
            int t = lut0[target[b]];
            float nll = (m + logf(s)) - lg0[t];
            float w = cw0[t];
            atomicAdd(accum + 0, w * nll);
            atomicAdd(accum + 1, w);
        }
    } else if (wv == 1) {
        // head1: 50 logits
        float x = (lane < K1) ? lg1[lane] : -3.0e38f;
        float m = waveReduceMax(x);
        float s = (lane < K1) ? expf(x - m) : 0.f;
        s = waveReduceSum(s);
        if (lane == 0) {
            int t = lut1[target[b]];
            float nll = (m + logf(s)) - lg1[t];
            float w = cw1[t];
            atomicAdd(accum + 2, w * nll);
            atomicAdd(accum + 3, w);
        }
    }
}

__global__ void finalize_kernel(const float* __restrict__ accum, float* __restrict__ out) {
    out[0] = accum[0] / accum[1] + accum[2] / accum[3];
}

extern "C" void kernel_launch(void* const* d_in, const int* in_sizes, int n_in,
                              void* d_out, int out_size, void* d_ws, size_t ws_size,
                              hipStream_t stream) {
    const float* feat0 = (const float*)d_in[0];
    const float* feat1 = (const float*)d_in[1];
    const float* W0    = (const float*)d_in[2];
    const float* b0    = (const float*)d_in[3];
    const float* W1    = (const float*)d_in[4];
    const float* b1    = (const float*)d_in[5];
    const int*   lut0  = (const int*)d_in[6];
    const int*   lut1  = (const int*)d_in[7];
    const float* cw0   = (const float*)d_in[8];
    const float* cw1   = (const float*)d_in[9];
    const int*   target= (const int*)d_in[10];

    // ws layout: pooled0 (BATCH*C0 f32 = 2 MB) | pooled1 (BATCH*C1 f32 = 4 MB) | accum (4 f32)
    float* pooled0 = (float*)d_ws;
    float* pooled1 = pooled0 + (size_t)BATCH * C0;
    float* accum   = pooled1 + (size_t)BATCH * C1;

    pool_fused_kernel<<<G0_BLOCKS + G1_BLOCKS, 256, 0, stream>>>(feat0, feat1,
                                                                 pooled0, pooled1, accum);
    head_ce_kernel<<<BATCH, 256, 0, stream>>>(pooled0, pooled1, W0, b0, W1, b1,
                                              lut0, lut1, cw0, cw1, target, accum);
    finalize_kernel<<<1, 1, 0, stream>>>(accum, (float*)d_out);
}

// Round 9
// 779.807 us; speedup vs baseline: 1.0025x; 1.0025x over previous
//
#include <hip/hip_runtime.h>
#include <math.h>

#define BATCH 1024
#define C0 512
#define HW0 196   // 14*14
#define C1 1024
#define HW1 49    // 7*7
#define K0 100
#define K1 50

// Fused pool grid: every wave handles a group of 4 consecutive channels.
// feat0: group = 4 ch x 49 float4 = 196 float4 (3136 B). feat1: group = 4 ch x 49 floats
// = 49 float4 (784 B). 4 waves per block.
#define G0_GROUPS (BATCH * C0 / 4)          // 131072 waves
#define G1_GROUPS (BATCH * C1 / 4)          // 262144 waves
#define G0_BLOCKS (G0_GROUPS / 4)           // 32768 blocks
#define G1_BLOCKS (G1_GROUPS / 4)           // 65536 blocks

__device__ __forceinline__ float waveReduceSum(float v) {
#pragma unroll
    for (int off = 32; off > 0; off >>= 1) v += __shfl_xor(v, off, 64);
    return v;
}
__device__ __forceinline__ float waveReduceMax(float v) {
#pragma unroll
    for (int off = 32; off > 0; off >>= 1) v = fmaxf(v, __shfl_xor(v, off, 64));
    return v;
}

__device__ __forceinline__ float sum4(float4 v) { return (v.x + v.y) + (v.z + v.w); }

// Fused global-average-pool.
// feat0 path: one wave per 4 consecutive channels = 196 float4. Lane l loads f4[l],
//   f4[l+64], f4[l+128] (all 64 lanes) and f4[l+192] (lanes 0-3). Channel of f4 index i
//   is i/49 -> resolved by lane-threshold compares into 4 accumulators (predicated adds,
//   stays in VGPRs). 4 wave reductions, one float4 store of the means.
// feat1 path: one wave per 4 consecutive channels = 49 aligned float4; per-lane segmented
//   add over the 4 floats of the lane's float4 (element e belongs to channel e/49).
__global__ __launch_bounds__(256) void pool_fused_kernel(const float* __restrict__ feat0,
                                                         const float* __restrict__ feat1,
                                                         float* __restrict__ pooled0,
                                                         float* __restrict__ pooled1,
                                                         float* __restrict__ accum) {
    if (blockIdx.x == 0 && threadIdx.x < 4) accum[threadIdx.x] = 0.f;  // zero loss accumulators
    const int lane = threadIdx.x & 63;
    const int wv   = threadIdx.x >> 6;

    if (blockIdx.x < G0_BLOCKS) {
        const int g = (blockIdx.x << 2) + wv;   // group of 4 feat0 channels
        const float4* p = reinterpret_cast<const float4*>(feat0) + (size_t)g * 196;
        // issue all loads up front (independent -> overlapped in flight)
        float4 v0 = p[lane];
        float4 v1 = p[lane + 64];
        float4 v2 = p[lane + 128];
        float4 v3 = (lane < 4) ? p[lane + 192] : make_float4(0.f, 0.f, 0.f, 0.f);
        float a0 = 0.f, a1 = 0.f, a2 = 0.f, a3 = 0.f;
        float s;
        s = sum4(v0); if (lane < 49) a0 += s; else a1 += s;   // idx l      : ch 0|1 @49
        s = sum4(v1); if (lane < 34) a1 += s; else a2 += s;   // idx l+64   : ch 1|2 @98
        s = sum4(v2); if (lane < 19) a2 += s; else a3 += s;   // idx l+128  : ch 2|3 @147
        a3 += sum4(v3);                                       // idx l+192  : ch 3 (lanes 0-3)
        a0 = waveReduceSum(a0);
        a1 = waveReduceSum(a1);
        a2 = waveReduceSum(a2);
        a3 = waveReduceSum(a3);
        if (lane == 0) {
            const float inv = 1.f / 196.f;
            float4 o;
            o.x = a0 * inv; o.y = a1 * inv; o.z = a2 * inv; o.w = a3 * inv;
            reinterpret_cast<float4*>(pooled0)[g] = o;
        }
    } else {
        const int g = ((blockIdx.x - G0_BLOCKS) << 2) + wv;  // group of 4 feat1 channels
        float a0 = 0.f, a1 = 0.f, a2 = 0.f, a3 = 0.f;
        if (lane < 49) {
            float4 v = reinterpret_cast<const float4*>(feat1)[(size_t)g * 49 + lane];
            const int e = lane * 4;
            float vv[4] = {v.x, v.y, v.z, v.w};
#pragma unroll
            for (int j = 0; j < 4; ++j) {
                int ej = e + j;
                int c = (ej >= 147) ? 3 : (ej >= 98) ? 2 : (ej >= 49) ? 1 : 0;
                float x = vv[j];
                a0 += (c == 0) ? x : 0.f;
                a1 += (c == 1) ? x : 0.f;
                a2 += (c == 2) ? x : 0.f;
                a3 += (c == 3) ? x : 0.f;
            }
        }
        a0 = waveReduceSum(a0);
        a1 = waveReduceSum(a1);
        a2 = waveReduceSum(a2);
        a3 = waveReduceSum(a3);
        if (lane == 0) {
            const float inv = 1.f / 49.f;
            float4 o;
            o.x = a0 * inv; o.y = a1 * inv; o.z = a2 * inv; o.w = a3 * inv;
            reinterpret_cast<float4*>(pooled1)[g] = o;
        }
    }
}

// One block per batch row. Stage pooled rows in LDS; thread k computes logit k
// (W0/W1 total 400KB -> L2-resident, reused by all 1024 blocks). Wave 0 / wave 1
// do the two log-sum-exp + weighted NLL reductions and atomicAdd 4 scalars.
__global__ __launch_bounds__(256) void head_ce_kernel(
    const float* __restrict__ pooled0, const float* __restrict__ pooled1,
    const float* __restrict__ W0, const float* __restrict__ b0,
    const float* __restrict__ W1, const float* __restrict__ b1,
    const int* __restrict__ lut0, const int* __restrict__ lut1,
    const float* __restrict__ cw0, const float* __restrict__ cw1,
    const int* __restrict__ target, float* __restrict__ accum) {
    __shared__ float sp0[C0];
    __shared__ float sp1[C1];
    __shared__ float lg0[K0];
    __shared__ float lg1[K1];
    const int b = blockIdx.x;
    const int tid = threadIdx.x;

    for (int i = tid; i < C0; i += 256) sp0[i] = pooled0[(size_t)b * C0 + i];
    for (int i = tid; i < C1; i += 256) sp1[i] = pooled1[(size_t)b * C1 + i];
    __syncthreads();

    if (tid < K0) {
        const float* w = W0 + (size_t)tid * C0;
        float acc0 = 0.f, acc1 = 0.f, acc2 = 0.f, acc3 = 0.f;
        for (int c = 0; c < C0; c += 4) {
            acc0 += sp0[c + 0] * w[c + 0];
            acc1 += sp0[c + 1] * w[c + 1];
            acc2 += sp0[c + 2] * w[c + 2];
            acc3 += sp0[c + 3] * w[c + 3];
        }
        lg0[tid] = b0[tid] + ((acc0 + acc1) + (acc2 + acc3));
    } else if (tid >= 128 && tid < 128 + K1) {
        const int k = tid - 128;
        const float* w = W1 + (size_t)k * C1;
        float acc0 = 0.f, acc1 = 0.f, acc2 = 0.f, acc3 = 0.f;
        for (int c = 0; c < C1; c += 4) {
            acc0 += sp1[c + 0] * w[c + 0];
            acc1 += sp1[c + 1] * w[c + 1];
            acc2 += sp1[c + 2] * w[c + 2];
            acc3 += sp1[c + 3] * w[c + 3];
        }
        lg1[k] = b1[k] + ((acc0 + acc1) + (acc2 + acc3));
    }
    __syncthreads();

    const int wv = tid >> 6;
    const int lane = tid & 63;
    if (wv == 0) {
        // head0: 100 logits, lanes cover [l, l+64]
        float x1 = lg0[lane];  // lane < 64 < K0
        bool has2 = (lane + 64) < K0;
        float x2 = has2 ? lg0[lane + 64] : -3.0e38f;
        float m = waveReduceMax(fmaxf(x1, x2));
        float s = expf(x1 - m) + (has2 ? expf(x2 - m) : 0.f);
        s = waveReduceSum(s);
        if (lane == 0) {
            int t = lut0[target[b]];
            float nll = (m + logf(s)) - lg0[t];
            float w = cw0[t];
            atomicAdd(accum + 0, w * nll);
            atomicAdd(accum + 1, w);
        }
    } else if (wv == 1) {
        // head1: 50 logits
        float x = (lane < K1) ? lg1[lane] : -3.0e38f;
        float m = waveReduceMax(x);
        float s = (lane < K1) ? expf(x - m) : 0.f;
        s = waveReduceSum(s);
        if (lane == 0) {
            int t = lut1[target[b]];
            float nll = (m + logf(s)) - lg1[t];
            float w = cw1[t];
            atomicAdd(accum + 2, w * nll);
            atomicAdd(accum + 3, w);
        }
    }
}

__global__ void finalize_kernel(const float* __restrict__ accum, float* __restrict__ out) {
    out[0] = accum[0] / accum[1] + accum[2] / accum[3];
}

extern "C" void kernel_launch(void* const* d_in, const int* in_sizes, int n_in,
                              void* d_out, int out_size, void* d_ws, size_t ws_size,
                              hipStream_t stream) {
    const float* feat0 = (const float*)d_in[0];
    const float* feat1 = (const float*)d_in[1];
    const float* W0    = (const float*)d_in[2];
    const float* b0    = (const float*)d_in[3];
    const float* W1    = (const float*)d_in[4];
    const float* b1    = (const float*)d_in[5];
    const int*   lut0  = (const int*)d_in[6];
    const int*   lut1  = (const int*)d_in[7];
    const float* cw0   = (const float*)d_in[8];
    const float* cw1   = (const float*)d_in[9];
    const int*   target= (const int*)d_in[10];

    // ws layout: pooled0 (BATCH*C0 f32 = 2 MB) | pooled1 (BATCH*C1 f32 = 4 MB) | accum (4 f32)
    float* pooled0 = (float*)d_ws;
    float* pooled1 = pooled0 + (size_t)BATCH * C0;
    float* accum   = pooled1 + (size_t)BATCH * C1;

    pool_fused_kernel<<<G0_BLOCKS + G1_BLOCKS, 256, 0, stream>>>(feat0, feat1,
                                                                 pooled0, pooled1, accum);
    head_ce_kernel<<<BATCH, 256, 0, stream>>>(pooled0, pooled1, W0, b0, W1, b1,
                                              lut0, lut1, cw0, cw1, target, accum);
    finalize_kernel<<<1, 1, 0, stream>>>(accum, (float*)d_out);
}